// Round 2
// baseline (2628.037 us; speedup 1.0000x reference)
//
#include <hip/hip_runtime.h>

// ---------------------------------------------------------------------------
// InteractionBlock: W = ssp(attr@w1+b1)@w2+b2; W *= cutoff(len);
// h = x@lin1_w; agg[dst] += h[src]*W; out = ssp(agg@lin2_w+b)@lin_w+b
// N=50000, E=1.6M, HID=NF=128, NG=64
// R4: pull (counting-sort by dst + one wave per node) with REGISTER DIET.
//     R3 spilled: __launch_bounds__(512,4) caps unified VGPR+AGPR at 128;
//     R3's live set (~130) crossed it -> ~4GB scratch traffic (WRITE_SIZE
//     1.95GB vs 26MB program writes). Diet: biases live in LDS (-16 VGPR),
//     epilogue meta loaded after MFMA section (-8 VGPR at peak).
// ---------------------------------------------------------------------------

typedef __attribute__((ext_vector_type(8))) short bf16x8;
typedef __attribute__((ext_vector_type(4))) float f32x4;

static __device__ __forceinline__ float sspf(float v) {
    return fmaxf(v, 0.0f) + __logf(1.0f + __expf(-fabsf(v))) - 0.69314718f;
}

// fp32 -> bf16 round-to-nearest-even
static __device__ __forceinline__ short bf16s(float x) {
    unsigned u = __builtin_bit_cast(unsigned, x);
    return (short)((u + 0x7fffu + ((u >> 16) & 1u)) >> 16);
}

// ---------------------------------------------------------------------------
// Kernel 1: h = x @ lin1_w   [N,128] = [N,128]@[128,128]  (fp32 vector)
// ---------------------------------------------------------------------------
__global__ __launch_bounds__(256) void node_proj_kernel(
    const float* __restrict__ x, const float* __restrict__ w,
    float* __restrict__ h, int n)
{
    __shared__ float xsT[128 * 20];   // [k][row], pitch 20 floats
    int row0 = blockIdx.x * 16;
    for (int i = threadIdx.x; i < 2048; i += 256) {
        int r = i >> 7, c = i & 127;
        int rr = row0 + r;
        xsT[c * 20 + r] = (rr < n) ? x[(size_t)rr * 128 + c] : 0.0f;
    }
    __syncthreads();
    int j = threadIdx.x & 127;
    int rb = (threadIdx.x >> 7) * 8;
    float acc[8] = {0, 0, 0, 0, 0, 0, 0, 0};
    for (int k = 0; k < 128; ++k) {
        float wk = w[k * 128 + j];
        const float4* xp = (const float4*)&xsT[k * 20 + rb];
        float4 u0 = xp[0], u1 = xp[1];
        acc[0] = fmaf(u0.x, wk, acc[0]);
        acc[1] = fmaf(u0.y, wk, acc[1]);
        acc[2] = fmaf(u0.z, wk, acc[2]);
        acc[3] = fmaf(u0.w, wk, acc[3]);
        acc[4] = fmaf(u1.x, wk, acc[4]);
        acc[5] = fmaf(u1.y, wk, acc[5]);
        acc[6] = fmaf(u1.z, wk, acc[6]);
        acc[7] = fmaf(u1.w, wk, acc[7]);
    }
#pragma unroll
    for (int r = 0; r < 8; ++r) {
        int rr = row0 + rb + r;
        if (rr < n) h[(size_t)rr * 128 + j] = acc[r];
    }
}

// ---------------------------------------------------------------------------
// Sort machinery: counting sort of edges by dst.
// ---------------------------------------------------------------------------
__global__ __launch_bounds__(256) void hist_kernel(
    const int* __restrict__ eidx, int* __restrict__ counts, int E)
{
    int i = blockIdx.x * 256 + threadIdx.x;
    int stride = gridDim.x * 256;
    for (; i < E; i += stride) atomicAdd(&counts[eidx[E + i]], 1);
}

// exclusive scan of counts[0..n-1] -> off[0..n] and cursor copy; 1 block.
__global__ __launch_bounds__(1024) void scan_kernel(
    const int* __restrict__ counts, int* __restrict__ off,
    int* __restrict__ cursor, int n)
{
    __shared__ int wsum[16];
    __shared__ int carry_s;
    int t = threadIdx.x;
    int lane = t & 63, w = t >> 6;
    if (t == 0) carry_s = 0;
    __syncthreads();
    for (int base = 0; base < n; base += 1024) {
        int idx = base + t;
        int v = (idx < n) ? counts[idx] : 0;
        int s = v;
#pragma unroll
        for (int d = 1; d < 64; d <<= 1) {
            int u = __shfl_up(s, d, 64);
            if (lane >= d) s += u;
        }
        if (lane == 63) wsum[w] = s;
        __syncthreads();
        if (w == 0) {
            int ws = (lane < 16) ? wsum[lane] : 0;
#pragma unroll
            for (int d = 1; d < 16; d <<= 1) {
                int u = __shfl_up(ws, d, 64);
                if (lane >= d) ws += u;
            }
            if (lane < 16) wsum[lane] = ws;   // inclusive wave totals
        }
        __syncthreads();
        int waveoff = (w > 0) ? wsum[w - 1] : 0;
        int total = wsum[15];
        int excl = carry_s + waveoff + s - v;
        if (idx < n) { off[idx] = excl; cursor[idx] = excl; }
        __syncthreads();                       // all reads of wsum/carry done
        if (t == 0) carry_s += total;
        __syncthreads();                       // carry visible; wsum reusable
    }
    if (t == 0) off[n] = carry_s;
}

__global__ __launch_bounds__(256) void reorder_kernel(
    const int* __restrict__ eidx, const float* __restrict__ elen,
    int* __restrict__ cursor, int* __restrict__ srcS,
    int* __restrict__ permS, float* __restrict__ cvS, int E)
{
    int i = blockIdx.x * 256 + threadIdx.x;
    int stride = gridDim.x * 256;
    for (; i < E; i += stride) {
        int dst = eidx[E + i];
        int pos = atomicAdd(&cursor[dst], 1);
        srcS[pos] = eidx[i];
        permS[pos] = i;
        float len = elen[i];
        bool ok = (len <= 10.0f) && (len >= 0.0f);
        cvS[pos] = ok ? 0.5f * (__cosf(len * 0.31415927f) + 1.0f) : 0.0f;
    }
}

// ---------------------------------------------------------------------------
// Kernel 2 (pull): one wave per dst node. Batches of 16 sorted edges through
// the MFMA edge-MLP; accumulate h[src]*W*cv in registers; one store per node.
// mfma_f32_16x16x32_bf16:  A[m=lane&15][k=(lane>>4)*8+j],
//                          B[k][n=lane&15], C/D row=(lane>>4)*4+reg, col=lane&15.
// Register budget (launch_bounds(512,4) -> <=128 unified/wave):
//   af 8 + acc2 32(AGPR) + acc1 8 + aggv 8 + addressing ~15 + transients
//   -> ~105. Biases live in LDS; epilogue meta loaded post-MFMA (transient).
// ---------------------------------------------------------------------------
__global__ __launch_bounds__(512, 4) void pull_kernel(
    const float* __restrict__ eattr, const int* __restrict__ srcS,
    const int* __restrict__ permS, const float* __restrict__ cvS,
    const int* __restrict__ off,
    const float* __restrict__ w1, const float* __restrict__ b1,
    const float* __restrict__ w2, const float* __restrict__ b2,
    const float* __restrict__ h, float* __restrict__ agg, int n)
{
    __shared__ short w1T[128 * 72];       // w1T[n][k], k<64   : 18 KB
    __shared__ short w2T[128 * 136];      // w2T[n][k], k<128  : 34 KB
    __shared__ short tseg[8 * 16 * 40];   // per-wave [edge][c] : 10 KB
    __shared__ float b1s[128], b2s[128];  // biases (f32)       : 1 KB

    for (int i = threadIdx.x; i < 64 * 128; i += 512) {
        int k = i >> 7, nn = i & 127;
        w1T[nn * 72 + k] = bf16s(w1[i]);
    }
    for (int i = threadIdx.x; i < 128 * 128; i += 512) {
        int k = i >> 7, nn = i & 127;
        w2T[nn * 136 + k] = bf16s(w2[i]);
    }
    if (threadIdx.x < 128) {
        b1s[threadIdx.x] = b1[threadIdx.x];
        b2s[threadIdx.x] = b2[threadIdx.x];
    }
    __syncthreads();

    const int lane = threadIdx.x & 63;
    const int m = lane & 15;        // edge-in-batch (A row) / output col partner
    const int q = lane >> 4;        // k-quad
    short* tw = tseg + (threadIdx.x >> 6) * (16 * 40);

    int wid = blockIdx.x * 8 + (threadIdx.x >> 6);
    int nwaves = gridDim.x * 8;

    for (int node = wid; node < n; node += nwaves) {
        int o0 = off[node], o1 = off[node + 1];

        float aggv[8] = {0, 0, 0, 0, 0, 0, 0, 0};

        for (int b0 = o0; b0 < o1; b0 += 16) {
            // ---- A fragments: sorted edge b0+m -> original row permS[...]
            int pa = b0 + m;
            if (pa >= o1) pa = o1 - 1;
            int pe = permS[pa];
            const float* ap = eattr + (size_t)pe * 64 + q * 8;
            float4 x0 = *(const float4*)(ap);
            float4 x1 = *(const float4*)(ap + 4);
            float4 x2 = *(const float4*)(ap + 32);
            float4 x3 = *(const float4*)(ap + 36);
            bf16x8 af0, af1;
            af0[0] = bf16s(x0.x); af0[1] = bf16s(x0.y);
            af0[2] = bf16s(x0.z); af0[3] = bf16s(x0.w);
            af0[4] = bf16s(x1.x); af0[5] = bf16s(x1.y);
            af0[6] = bf16s(x1.z); af0[7] = bf16s(x1.w);
            af1[0] = bf16s(x2.x); af1[1] = bf16s(x2.y);
            af1[2] = bf16s(x2.z); af1[3] = bf16s(x2.w);
            af1[4] = bf16s(x3.x); af1[5] = bf16s(x3.y);
            af1[6] = bf16s(x3.z); af1[7] = bf16s(x3.w);

            // ---- layer-2 accumulators (W), init with b2 from LDS
            f32x4 acc2[8];
#pragma unroll
            for (int nt = 0; nt < 8; ++nt) {
                float bv2 = b2s[nt * 16 + m];
                f32x4 c; c[0] = bv2; c[1] = bv2; c[2] = bv2; c[3] = bv2;
                acc2[nt] = c;
            }

            // ---- fused layer1 -> ssp -> layer2, 32 t-columns at a time
#pragma unroll
            for (int k2 = 0; k2 < 4; ++k2) {
                f32x4 acc1[2];
#pragma unroll
                for (int t = 0; t < 2; ++t) {
                    float bv = b1s[(2 * k2 + t) * 16 + m];
                    f32x4 c; c[0] = bv; c[1] = bv; c[2] = bv; c[3] = bv;
                    acc1[t] = c;
                }
#pragma unroll
                for (int t = 0; t < 2; ++t) {
#pragma unroll
                    for (int a = 0; a < 2; ++a) {
                        bf16x8 bw = *(const bf16x8*)&w1T[(16 * (2 * k2 + t) + m) * 72 + a * 32 + q * 8];
                        acc1[t] = __builtin_amdgcn_mfma_f32_16x16x32_bf16(
                            (a == 0) ? af0 : af1, bw, acc1[t], 0, 0, 0);
                    }
                }
#pragma unroll
                for (int t = 0; t < 2; ++t) {
#pragma unroll
                    for (int r = 0; r < 4; ++r) {
                        tw[(4 * q + r) * 40 + 16 * t + m] = bf16s(sspf(acc1[t][r]));
                    }
                }
                bf16x8 ta = *(const bf16x8*)&tw[m * 40 + q * 8];
#pragma unroll
                for (int nt = 0; nt < 8; ++nt) {
                    bf16x8 bw2 = *(const bf16x8*)&w2T[(16 * nt + m) * 136 + k2 * 32 + q * 8];
                    acc2[nt] = __builtin_amdgcn_mfma_f32_16x16x32_bf16(ta, bw2, acc2[nt], 0, 0, 0);
                }
            }

            // ---- epilogue meta (loaded AFTER MFMA section: transient regs)
            float cvv[4];
            int sV[4];
#pragma unroll
            for (int r = 0; r < 4; ++r) {
                int p = b0 + 4 * q + r;
                bool valid = (p < o1);
                int pc = valid ? p : o0;
                cvv[r] = valid ? cvS[pc] : 0.0f;
                sV[r] = srcS[pc];
            }

            // ---- accumulate msg into registers (no atomics)
#pragma unroll
            for (int r = 0; r < 4; ++r) {
                float cv = cvv[r];
                if (cv != 0.0f) {
                    const float* hp = h + (size_t)sV[r] * 128 + m;
#pragma unroll
                    for (int nt = 0; nt < 8; ++nt) {
                        aggv[nt] = fmaf(hp[nt * 16], acc2[nt][r] * cv, aggv[nt]);
                    }
                }
            }
        }

        // ---- reduce partials across the 4 k-quads (lanes m, m+16, m+32, m+48)
#pragma unroll
        for (int nt = 0; nt < 8; ++nt) {
            float v = aggv[nt];
            v += __shfl_xor(v, 16, 64);
            v += __shfl_xor(v, 32, 64);
            aggv[nt] = v;
        }
        // lane (m,q) writes cols 32q+m (nt=2q) and 32q+16+m (nt=2q+1):
        // union over lanes = all 128 cols, two coalesced 256B stores.
        float wA, wB;
        if (q == 0)      { wA = aggv[0]; wB = aggv[1]; }
        else if (q == 1) { wA = aggv[2]; wB = aggv[3]; }
        else if (q == 2) { wA = aggv[4]; wB = aggv[5]; }
        else             { wA = aggv[6]; wB = aggv[7]; }
        float* gp = agg + (size_t)node * 128;
        gp[32 * q + m] = wA;
        gp[32 * q + 16 + m] = wB;
    }
}

// ---------------------------------------------------------------------------
// Kernel 3: out = ssp(agg @ lin2_w + lin2_b) @ lin_w + lin_b  (fp32 vector)
// ---------------------------------------------------------------------------
__global__ __launch_bounds__(256) void out_kernel(
    const float* __restrict__ agg,
    const float* __restrict__ w2, const float* __restrict__ b2,
    const float* __restrict__ w3, const float* __restrict__ b3,
    float* __restrict__ out, int n)
{
    __shared__ float aT[128 * 20];
    __shared__ float mT[128 * 20];
    int row0 = blockIdx.x * 16;
    for (int i = threadIdx.x; i < 2048; i += 256) {
        int r = i >> 7, c = i & 127;
        int rr = row0 + r;
        aT[c * 20 + r] = (rr < n) ? agg[(size_t)rr * 128 + c] : 0.0f;
    }
    __syncthreads();
    int j = threadIdx.x & 127;
    int rb = (threadIdx.x >> 7) * 8;

    float acc[8];
    float bj = b2[j];
#pragma unroll
    for (int r = 0; r < 8; ++r) acc[r] = bj;
    for (int k = 0; k < 128; ++k) {
        float wk = w2[k * 128 + j];
        const float4* xp = (const float4*)&aT[k * 20 + rb];
        float4 u0 = xp[0], u1 = xp[1];
        acc[0] = fmaf(u0.x, wk, acc[0]);
        acc[1] = fmaf(u0.y, wk, acc[1]);
        acc[2] = fmaf(u0.z, wk, acc[2]);
        acc[3] = fmaf(u0.w, wk, acc[3]);
        acc[4] = fmaf(u1.x, wk, acc[4]);
        acc[5] = fmaf(u1.y, wk, acc[5]);
        acc[6] = fmaf(u1.z, wk, acc[6]);
        acc[7] = fmaf(u1.w, wk, acc[7]);
    }
    float4 s0, s1;
    s0.x = sspf(acc[0]); s0.y = sspf(acc[1]); s0.z = sspf(acc[2]); s0.w = sspf(acc[3]);
    s1.x = sspf(acc[4]); s1.y = sspf(acc[5]); s1.z = sspf(acc[6]); s1.w = sspf(acc[7]);
    ((float4*)&mT[j * 20 + rb])[0] = s0;
    ((float4*)&mT[j * 20 + rb])[1] = s1;
    __syncthreads();

    float bj3 = b3[j];
#pragma unroll
    for (int r = 0; r < 8; ++r) acc[r] = bj3;
    for (int k = 0; k < 128; ++k) {
        float wk = w3[k * 128 + j];
        const float4* xp = (const float4*)&mT[k * 20 + rb];
        float4 u0 = xp[0], u1 = xp[1];
        acc[0] = fmaf(u0.x, wk, acc[0]);
        acc[1] = fmaf(u0.y, wk, acc[1]);
        acc[2] = fmaf(u0.z, wk, acc[2]);
        acc[3] = fmaf(u0.w, wk, acc[3]);
        acc[4] = fmaf(u1.x, wk, acc[4]);
        acc[5] = fmaf(u1.y, wk, acc[5]);
        acc[6] = fmaf(u1.z, wk, acc[6]);
        acc[7] = fmaf(u1.w, wk, acc[7]);
    }
#pragma unroll
    for (int r = 0; r < 8; ++r) {
        int rr = row0 + rb + r;
        if (rr < n) out[(size_t)rr * 128 + j] = acc[r];
    }
}

// ---------------------------------------------------------------------------
extern "C" void kernel_launch(void* const* d_in, const int* in_sizes, int n_in,
                              void* d_out, int out_size, void* d_ws, size_t ws_size,
                              hipStream_t stream)
{
    const float* x     = (const float*)d_in[0];
    const int*   eidx  = (const int*)d_in[1];
    const float* elen  = (const float*)d_in[2];
    const float* eattr = (const float*)d_in[3];
    const float* lin1w = (const float*)d_in[4];
    const float* nnw1  = (const float*)d_in[5];
    const float* nnb1  = (const float*)d_in[6];
    const float* nnw2  = (const float*)d_in[7];
    const float* nnb2  = (const float*)d_in[8];
    const float* lin2w = (const float*)d_in[9];
    const float* lin2b = (const float*)d_in[10];
    const float* linw  = (const float*)d_in[11];
    const float* linb  = (const float*)d_in[12];

    int n = in_sizes[0] / 128;   // 50000
    int E = in_sizes[2];         // 1.6M

    // workspace layout (all 4B types): ~71 MB
    float* h      = (float*)d_ws;                 // n*128
    float* agg    = h + (size_t)n * 128;          // n*128
    int*   counts = (int*)(agg + (size_t)n * 128);// n
    int*   off    = counts + n;                   // n+1
    int*   cursor = off + n + 1;                  // n
    int*   srcS   = cursor + n;                   // E
    int*   permS  = srcS + E;                     // E
    float* cvS    = (float*)(permS + E);          // E

    hipMemsetAsync(counts, 0, (size_t)n * sizeof(int), stream);

    node_proj_kernel<<<(n + 15) / 16, 256, 0, stream>>>(x, lin1w, h, n);
    hist_kernel<<<2048, 256, 0, stream>>>(eidx, counts, E);
    scan_kernel<<<1, 1024, 0, stream>>>(counts, off, cursor, n);
    reorder_kernel<<<2048, 256, 0, stream>>>(eidx, elen, cursor, srcS, permS, cvS, E);
    pull_kernel<<<512, 512, 0, stream>>>(eattr, srcS, permS, cvS, off,
                                         nnw1, nnb1, nnw2, nnb2, h, agg, n);
    out_kernel<<<(n + 15) / 16, 256, 0, stream>>>(agg, lin2w, lin2b, linw, linb,
                                                  (float*)d_out, n);
}

// Round 3
// 1730.864 us; speedup vs baseline: 1.5183x; 1.5183x over previous
//
#include <hip/hip_runtime.h>

// ---------------------------------------------------------------------------
// InteractionBlock: W = ssp(attr@w1+b1)@w2+b2; W *= cutoff(len);
// h = x@lin1_w; agg[dst] += h[src]*W; out = ssp(agg@lin2_w+b)@lin_w+b
// N=50000, E=1.6M, HID=NF=128, NG=64
// R5: pull (counting-sort by dst + one wave per node).
//     R3/R4 post-mortem: __launch_bounds__(512,4) caps unified regs at 128;
//     the -O3 scheduler software-pipelines cross-batch loads and SPILLS
//     (~2.6GB writes vs 26MB program writes; duration insensitive to
//     occupancy 10% vs 42% => scratch-BW-bound). Register diet (R4) failed
//     because the ceiling, not the live set, is the constraint.
//     Single change: launch_bounds (512,2) -> 256-reg cap, no spill;
//     accept 1 block/CU (8 waves, LDS 63.5KB).
// ---------------------------------------------------------------------------

typedef __attribute__((ext_vector_type(8))) short bf16x8;
typedef __attribute__((ext_vector_type(4))) float f32x4;

static __device__ __forceinline__ float sspf(float v) {
    return fmaxf(v, 0.0f) + __logf(1.0f + __expf(-fabsf(v))) - 0.69314718f;
}

// fp32 -> bf16 round-to-nearest-even
static __device__ __forceinline__ short bf16s(float x) {
    unsigned u = __builtin_bit_cast(unsigned, x);
    return (short)((u + 0x7fffu + ((u >> 16) & 1u)) >> 16);
}

// ---------------------------------------------------------------------------
// Kernel 1: h = x @ lin1_w   [N,128] = [N,128]@[128,128]  (fp32 vector)
// ---------------------------------------------------------------------------
__global__ __launch_bounds__(256) void node_proj_kernel(
    const float* __restrict__ x, const float* __restrict__ w,
    float* __restrict__ h, int n)
{
    __shared__ float xsT[128 * 20];   // [k][row], pitch 20 floats
    int row0 = blockIdx.x * 16;
    for (int i = threadIdx.x; i < 2048; i += 256) {
        int r = i >> 7, c = i & 127;
        int rr = row0 + r;
        xsT[c * 20 + r] = (rr < n) ? x[(size_t)rr * 128 + c] : 0.0f;
    }
    __syncthreads();
    int j = threadIdx.x & 127;
    int rb = (threadIdx.x >> 7) * 8;
    float acc[8] = {0, 0, 0, 0, 0, 0, 0, 0};
    for (int k = 0; k < 128; ++k) {
        float wk = w[k * 128 + j];
        const float4* xp = (const float4*)&xsT[k * 20 + rb];
        float4 u0 = xp[0], u1 = xp[1];
        acc[0] = fmaf(u0.x, wk, acc[0]);
        acc[1] = fmaf(u0.y, wk, acc[1]);
        acc[2] = fmaf(u0.z, wk, acc[2]);
        acc[3] = fmaf(u0.w, wk, acc[3]);
        acc[4] = fmaf(u1.x, wk, acc[4]);
        acc[5] = fmaf(u1.y, wk, acc[5]);
        acc[6] = fmaf(u1.z, wk, acc[6]);
        acc[7] = fmaf(u1.w, wk, acc[7]);
    }
#pragma unroll
    for (int r = 0; r < 8; ++r) {
        int rr = row0 + rb + r;
        if (rr < n) h[(size_t)rr * 128 + j] = acc[r];
    }
}

// ---------------------------------------------------------------------------
// Sort machinery: counting sort of edges by dst.
// ---------------------------------------------------------------------------
__global__ __launch_bounds__(256) void hist_kernel(
    const int* __restrict__ eidx, int* __restrict__ counts, int E)
{
    int i = blockIdx.x * 256 + threadIdx.x;
    int stride = gridDim.x * 256;
    for (; i < E; i += stride) atomicAdd(&counts[eidx[E + i]], 1);
}

// exclusive scan of counts[0..n-1] -> off[0..n] and cursor copy; 1 block.
__global__ __launch_bounds__(1024) void scan_kernel(
    const int* __restrict__ counts, int* __restrict__ off,
    int* __restrict__ cursor, int n)
{
    __shared__ int wsum[16];
    __shared__ int carry_s;
    int t = threadIdx.x;
    int lane = t & 63, w = t >> 6;
    if (t == 0) carry_s = 0;
    __syncthreads();
    for (int base = 0; base < n; base += 1024) {
        int idx = base + t;
        int v = (idx < n) ? counts[idx] : 0;
        int s = v;
#pragma unroll
        for (int d = 1; d < 64; d <<= 1) {
            int u = __shfl_up(s, d, 64);
            if (lane >= d) s += u;
        }
        if (lane == 63) wsum[w] = s;
        __syncthreads();
        if (w == 0) {
            int ws = (lane < 16) ? wsum[lane] : 0;
#pragma unroll
            for (int d = 1; d < 16; d <<= 1) {
                int u = __shfl_up(ws, d, 64);
                if (lane >= d) ws += u;
            }
            if (lane < 16) wsum[lane] = ws;   // inclusive wave totals
        }
        __syncthreads();
        int waveoff = (w > 0) ? wsum[w - 1] : 0;
        int total = wsum[15];
        int excl = carry_s + waveoff + s - v;
        if (idx < n) { off[idx] = excl; cursor[idx] = excl; }
        __syncthreads();                       // all reads of wsum/carry done
        if (t == 0) carry_s += total;
        __syncthreads();                       // carry visible; wsum reusable
    }
    if (t == 0) off[n] = carry_s;
}

__global__ __launch_bounds__(256) void reorder_kernel(
    const int* __restrict__ eidx, const float* __restrict__ elen,
    int* __restrict__ cursor, int* __restrict__ srcS,
    int* __restrict__ permS, float* __restrict__ cvS, int E)
{
    int i = blockIdx.x * 256 + threadIdx.x;
    int stride = gridDim.x * 256;
    for (; i < E; i += stride) {
        int dst = eidx[E + i];
        int pos = atomicAdd(&cursor[dst], 1);
        srcS[pos] = eidx[i];
        permS[pos] = i;
        float len = elen[i];
        bool ok = (len <= 10.0f) && (len >= 0.0f);
        cvS[pos] = ok ? 0.5f * (__cosf(len * 0.31415927f) + 1.0f) : 0.0f;
    }
}

// ---------------------------------------------------------------------------
// Kernel 2 (pull): one wave per dst node. Batches of 16 sorted edges through
// the MFMA edge-MLP; accumulate h[src]*W*cv in registers; one store per node.
// mfma_f32_16x16x32_bf16:  A[m=lane&15][k=(lane>>4)*8+j],
//                          B[k][n=lane&15], C/D row=(lane>>4)*4+reg, col=lane&15.
// launch_bounds(512,2): 256-reg unified cap. The (512,4)/128-cap builds spill
// the compiler's cross-batch software pipeline to scratch (GBs of traffic).
// ---------------------------------------------------------------------------
__global__ __launch_bounds__(512, 2) void pull_kernel(
    const float* __restrict__ eattr, const int* __restrict__ srcS,
    const int* __restrict__ permS, const float* __restrict__ cvS,
    const int* __restrict__ off,
    const float* __restrict__ w1, const float* __restrict__ b1,
    const float* __restrict__ w2, const float* __restrict__ b2,
    const float* __restrict__ h, float* __restrict__ agg, int n)
{
    __shared__ short w1T[128 * 72];       // w1T[n][k], k<64   : 18 KB
    __shared__ short w2T[128 * 136];      // w2T[n][k], k<128  : 34 KB
    __shared__ short tseg[8 * 16 * 40];   // per-wave [edge][c] : 10 KB
    __shared__ float b1s[128], b2s[128];  // biases (f32)       : 1 KB

    for (int i = threadIdx.x; i < 64 * 128; i += 512) {
        int k = i >> 7, nn = i & 127;
        w1T[nn * 72 + k] = bf16s(w1[i]);
    }
    for (int i = threadIdx.x; i < 128 * 128; i += 512) {
        int k = i >> 7, nn = i & 127;
        w2T[nn * 136 + k] = bf16s(w2[i]);
    }
    if (threadIdx.x < 128) {
        b1s[threadIdx.x] = b1[threadIdx.x];
        b2s[threadIdx.x] = b2[threadIdx.x];
    }
    __syncthreads();

    const int lane = threadIdx.x & 63;
    const int m = lane & 15;        // edge-in-batch (A row) / output col partner
    const int q = lane >> 4;        // k-quad
    short* tw = tseg + (threadIdx.x >> 6) * (16 * 40);

    int wid = blockIdx.x * 8 + (threadIdx.x >> 6);
    int nwaves = gridDim.x * 8;

    for (int node = wid; node < n; node += nwaves) {
        int o0 = off[node], o1 = off[node + 1];

        float aggv[8] = {0, 0, 0, 0, 0, 0, 0, 0};

        for (int b0 = o0; b0 < o1; b0 += 16) {
            // ---- A fragments: sorted edge b0+m -> original row permS[...]
            int pa = b0 + m;
            if (pa >= o1) pa = o1 - 1;
            int pe = permS[pa];
            const float* ap = eattr + (size_t)pe * 64 + q * 8;
            float4 x0 = *(const float4*)(ap);
            float4 x1 = *(const float4*)(ap + 4);
            float4 x2 = *(const float4*)(ap + 32);
            float4 x3 = *(const float4*)(ap + 36);
            bf16x8 af0, af1;
            af0[0] = bf16s(x0.x); af0[1] = bf16s(x0.y);
            af0[2] = bf16s(x0.z); af0[3] = bf16s(x0.w);
            af0[4] = bf16s(x1.x); af0[5] = bf16s(x1.y);
            af0[6] = bf16s(x1.z); af0[7] = bf16s(x1.w);
            af1[0] = bf16s(x2.x); af1[1] = bf16s(x2.y);
            af1[2] = bf16s(x2.z); af1[3] = bf16s(x2.w);
            af1[4] = bf16s(x3.x); af1[5] = bf16s(x3.y);
            af1[6] = bf16s(x3.z); af1[7] = bf16s(x3.w);

            // ---- layer-2 accumulators (W), init with b2 from LDS
            f32x4 acc2[8];
#pragma unroll
            for (int nt = 0; nt < 8; ++nt) {
                float bv2 = b2s[nt * 16 + m];
                f32x4 c; c[0] = bv2; c[1] = bv2; c[2] = bv2; c[3] = bv2;
                acc2[nt] = c;
            }

            // ---- fused layer1 -> ssp -> layer2, 32 t-columns at a time
#pragma unroll
            for (int k2 = 0; k2 < 4; ++k2) {
                f32x4 acc1[2];
#pragma unroll
                for (int t = 0; t < 2; ++t) {
                    float bv = b1s[(2 * k2 + t) * 16 + m];
                    f32x4 c; c[0] = bv; c[1] = bv; c[2] = bv; c[3] = bv;
                    acc1[t] = c;
                }
#pragma unroll
                for (int t = 0; t < 2; ++t) {
#pragma unroll
                    for (int a = 0; a < 2; ++a) {
                        bf16x8 bw = *(const bf16x8*)&w1T[(16 * (2 * k2 + t) + m) * 72 + a * 32 + q * 8];
                        acc1[t] = __builtin_amdgcn_mfma_f32_16x16x32_bf16(
                            (a == 0) ? af0 : af1, bw, acc1[t], 0, 0, 0);
                    }
                }
#pragma unroll
                for (int t = 0; t < 2; ++t) {
#pragma unroll
                    for (int r = 0; r < 4; ++r) {
                        tw[(4 * q + r) * 40 + 16 * t + m] = bf16s(sspf(acc1[t][r]));
                    }
                }
                bf16x8 ta = *(const bf16x8*)&tw[m * 40 + q * 8];
#pragma unroll
                for (int nt = 0; nt < 8; ++nt) {
                    bf16x8 bw2 = *(const bf16x8*)&w2T[(16 * nt + m) * 136 + k2 * 32 + q * 8];
                    acc2[nt] = __builtin_amdgcn_mfma_f32_16x16x32_bf16(ta, bw2, acc2[nt], 0, 0, 0);
                }
            }

            // ---- epilogue meta (transient regs, loaded after MFMA section)
            float cvv[4];
            int sV[4];
#pragma unroll
            for (int r = 0; r < 4; ++r) {
                int p = b0 + 4 * q + r;
                bool valid = (p < o1);
                int pc = valid ? p : o0;
                cvv[r] = valid ? cvS[pc] : 0.0f;
                sV[r] = srcS[pc];
            }

            // ---- accumulate msg into registers (no atomics)
#pragma unroll
            for (int r = 0; r < 4; ++r) {
                float cv = cvv[r];
                if (cv != 0.0f) {
                    const float* hp = h + (size_t)sV[r] * 128 + m;
#pragma unroll
                    for (int nt = 0; nt < 8; ++nt) {
                        aggv[nt] = fmaf(hp[nt * 16], acc2[nt][r] * cv, aggv[nt]);
                    }
                }
            }
        }

        // ---- reduce partials across the 4 k-quads (lanes m, m+16, m+32, m+48)
#pragma unroll
        for (int nt = 0; nt < 8; ++nt) {
            float v = aggv[nt];
            v += __shfl_xor(v, 16, 64);
            v += __shfl_xor(v, 32, 64);
            aggv[nt] = v;
        }
        // lane (m,q) writes cols 32q+m (nt=2q) and 32q+16+m (nt=2q+1):
        // union over lanes = all 128 cols, two coalesced 256B stores.
        float wA, wB;
        if (q == 0)      { wA = aggv[0]; wB = aggv[1]; }
        else if (q == 1) { wA = aggv[2]; wB = aggv[3]; }
        else if (q == 2) { wA = aggv[4]; wB = aggv[5]; }
        else             { wA = aggv[6]; wB = aggv[7]; }
        float* gp = agg + (size_t)node * 128;
        gp[32 * q + m] = wA;
        gp[32 * q + 16 + m] = wB;
    }
}

// ---------------------------------------------------------------------------
// Kernel 3: out = ssp(agg @ lin2_w + lin2_b) @ lin_w + lin_b  (fp32 vector)
// ---------------------------------------------------------------------------
__global__ __launch_bounds__(256) void out_kernel(
    const float* __restrict__ agg,
    const float* __restrict__ w2, const float* __restrict__ b2,
    const float* __restrict__ w3, const float* __restrict__ b3,
    float* __restrict__ out, int n)
{
    __shared__ float aT[128 * 20];
    __shared__ float mT[128 * 20];
    int row0 = blockIdx.x * 16;
    for (int i = threadIdx.x; i < 2048; i += 256) {
        int r = i >> 7, c = i & 127;
        int rr = row0 + r;
        aT[c * 20 + r] = (rr < n) ? agg[(size_t)rr * 128 + c] : 0.0f;
    }
    __syncthreads();
    int j = threadIdx.x & 127;
    int rb = (threadIdx.x >> 7) * 8;

    float acc[8];
    float bj = b2[j];
#pragma unroll
    for (int r = 0; r < 8; ++r) acc[r] = bj;
    for (int k = 0; k < 128; ++k) {
        float wk = w2[k * 128 + j];
        const float4* xp = (const float4*)&aT[k * 20 + rb];
        float4 u0 = xp[0], u1 = xp[1];
        acc[0] = fmaf(u0.x, wk, acc[0]);
        acc[1] = fmaf(u0.y, wk, acc[1]);
        acc[2] = fmaf(u0.z, wk, acc[2]);
        acc[3] = fmaf(u0.w, wk, acc[3]);
        acc[4] = fmaf(u1.x, wk, acc[4]);
        acc[5] = fmaf(u1.y, wk, acc[5]);
        acc[6] = fmaf(u1.z, wk, acc[6]);
        acc[7] = fmaf(u1.w, wk, acc[7]);
    }
    float4 s0, s1;
    s0.x = sspf(acc[0]); s0.y = sspf(acc[1]); s0.z = sspf(acc[2]); s0.w = sspf(acc[3]);
    s1.x = sspf(acc[4]); s1.y = sspf(acc[5]); s1.z = sspf(acc[6]); s1.w = sspf(acc[7]);
    ((float4*)&mT[j * 20 + rb])[0] = s0;
    ((float4*)&mT[j * 20 + rb])[1] = s1;
    __syncthreads();

    float bj3 = b3[j];
#pragma unroll
    for (int r = 0; r < 8; ++r) acc[r] = bj3;
    for (int k = 0; k < 128; ++k) {
        float wk = w3[k * 128 + j];
        const float4* xp = (const float4*)&mT[k * 20 + rb];
        float4 u0 = xp[0], u1 = xp[1];
        acc[0] = fmaf(u0.x, wk, acc[0]);
        acc[1] = fmaf(u0.y, wk, acc[1]);
        acc[2] = fmaf(u0.z, wk, acc[2]);
        acc[3] = fmaf(u0.w, wk, acc[3]);
        acc[4] = fmaf(u1.x, wk, acc[4]);
        acc[5] = fmaf(u1.y, wk, acc[5]);
        acc[6] = fmaf(u1.z, wk, acc[6]);
        acc[7] = fmaf(u1.w, wk, acc[7]);
    }
#pragma unroll
    for (int r = 0; r < 8; ++r) {
        int rr = row0 + rb + r;
        if (rr < n) out[(size_t)rr * 128 + j] = acc[r];
    }
}

// ---------------------------------------------------------------------------
extern "C" void kernel_launch(void* const* d_in, const int* in_sizes, int n_in,
                              void* d_out, int out_size, void* d_ws, size_t ws_size,
                              hipStream_t stream)
{
    const float* x     = (const float*)d_in[0];
    const int*   eidx  = (const int*)d_in[1];
    const float* elen  = (const float*)d_in[2];
    const float* eattr = (const float*)d_in[3];
    const float* lin1w = (const float*)d_in[4];
    const float* nnw1  = (const float*)d_in[5];
    const float* nnb1  = (const float*)d_in[6];
    const float* nnw2  = (const float*)d_in[7];
    const float* nnb2  = (const float*)d_in[8];
    const float* lin2w = (const float*)d_in[9];
    const float* lin2b = (const float*)d_in[10];
    const float* linw  = (const float*)d_in[11];
    const float* linb  = (const float*)d_in[12];

    int n = in_sizes[0] / 128;   // 50000
    int E = in_sizes[2];         // 1.6M

    // workspace layout (all 4B types): ~71 MB
    float* h      = (float*)d_ws;                 // n*128
    float* agg    = h + (size_t)n * 128;          // n*128
    int*   counts = (int*)(agg + (size_t)n * 128);// n
    int*   off    = counts + n;                   // n+1
    int*   cursor = off + n + 1;                  // n
    int*   srcS   = cursor + n;                   // E
    int*   permS  = srcS + E;                     // E
    float* cvS    = (float*)(permS + E);          // E

    hipMemsetAsync(counts, 0, (size_t)n * sizeof(int), stream);

    node_proj_kernel<<<(n + 15) / 16, 256, 0, stream>>>(x, lin1w, h, n);
    hist_kernel<<<2048, 256, 0, stream>>>(eidx, counts, E);
    scan_kernel<<<1, 1024, 0, stream>>>(counts, off, cursor, n);
    reorder_kernel<<<2048, 256, 0, stream>>>(eidx, elen, cursor, srcS, permS, cvS, E);
    pull_kernel<<<512, 512, 0, stream>>>(eattr, srcS, permS, cvS, off,
                                         nnw1, nnb1, nnw2, nnb2, h, agg, n);
    out_kernel<<<(n + 15) / 16, 256, 0, stream>>>(agg, lin2w, lin2b, linw, linb,
                                                  (float*)d_out, n);
}